// Round 3
// baseline (779.024 us; speedup 1.0000x reference)
//
#include <hip/hip_runtime.h>
#include <hip/hip_bf16.h>
#include <cstdint>

#define N_NODES 100000
#define N_EDGES 1600000
#define N_GRAPHS 2000
#define IN_DIM 37
#define HID 128

typedef __attribute__((ext_vector_type(8))) short short8;
typedef __attribute__((ext_vector_type(4))) float f32x4;

static __device__ __forceinline__ short bf16_bits(float f) {
    __hip_bfloat16 h = __float2bfloat16(f);
    return *reinterpret_cast<short*>(&h);
}
static __device__ __forceinline__ float bf16_lo(uint32_t u) {
    uint32_t v = u << 16;
    return *reinterpret_cast<float*>(&v);
}
static __device__ __forceinline__ float bf16_hi(uint32_t u) {
    uint32_t v = u & 0xffff0000u;
    return *reinterpret_cast<float*>(&v);
}

// ---------------- init: head = -1 ----------------

__global__ __launch_bounds__(256) void init_head(int* __restrict__ head) {
    int i = blockIdx.x * 256 + threadIdx.x;
    if (i < N_NODES) head[i] = -1;
}

// ---------------- fused: fill (linked list) + x convert + weight pack ----------------

#define FILL_BLOCKS 6250   // 1.6M edges / 256
#define CONV_BLOCKS 6250   // 1.6M quad-tasks (100k nodes x 16 quads)
#define PACK_BLOCKS 480    // 30*4096/256

struct PackArgs {
    const float* w[9];
    short* o[9];
};

__global__ __launch_bounds__(256) void fused_prep(const int* __restrict__ ei,
                                                  int* __restrict__ head,
                                                  int2* __restrict__ edge_rec,
                                                  const float* __restrict__ x,
                                                  short* __restrict__ Xb,
                                                  PackArgs pa) {
    const int b = blockIdx.x;
    const int tid = threadIdx.x;

    if (b < FILL_BLOCKS) {
        const int e = b * 256 + tid;
        const int s = ei[e];
        const int d = ei[N_EDGES + e];
        const int old = atomicExch(&head[d], e);
        edge_rec[e] = make_int2(s, old);
        return;
    }
    if (b < FILL_BLOCKS + CONV_BLOCKS) {
        const int idx = (b - FILL_BLOCKS) * 256 + tid;  // 0..1.6M
        const int n = idx >> 4, j = idx & 15;
        const int k0 = j * 4;
        short4 o;
        o.x = (k0 + 0 < IN_DIM) ? bf16_bits(x[(size_t)n * IN_DIM + k0 + 0]) : (short)0;
        o.y = (k0 + 1 < IN_DIM) ? bf16_bits(x[(size_t)n * IN_DIM + k0 + 1]) : (short)0;
        o.z = (k0 + 2 < IN_DIM) ? bf16_bits(x[(size_t)n * IN_DIM + k0 + 2]) : (short)0;
        o.w = (k0 + 3 < IN_DIM) ? bf16_bits(x[(size_t)n * IN_DIM + k0 + 3]) : (short)0;
        *(short4*)(Xb + (size_t)n * 64 + k0) = o;
        return;
    }
    // pack: packed[kb*4096 + t*512 + lane*8 + i] = bf16(W[kb*32+(lane>>4)*8+i][t*16+(lane&15)])
    int idx = (b - FILL_BLOCKS - CONV_BLOCKS) * 256 + tid;  // 0..122880
    // matrix sizes: first 3 are 8192 (K32=2), next 6 are 16384 (K32=4)
    int m, r, kin;
    if (idx < 24576) {
        m = idx >> 13;          // /8192
        r = idx & 8191;
        kin = IN_DIM;
    } else {
        int q = idx - 24576;
        m = 3 + (q >> 14);      // /16384
        r = q & 16383;
        kin = HID;
    }
    const int i = r & 7, lane = (r >> 3) & 63, t = (r >> 9) & 7, kb = r >> 12;
    const int k = kb * 32 + (lane >> 4) * 8 + i;
    const int c = t * 16 + (lane & 15);
    float v = (k < kin) ? pa.w[m][(size_t)k * HID + c] : 0.f;
    pa.o[m][r] = bf16_bits(v);
}

// ---------------- fused LEConv GEMM (MFMA bf16, fp32 accum) ----------------
// D = h@W1 + b1 (fp32), E = h@W3 + b3 (bf16), B = h@W2 (bf16)

template <int K32>
__global__ __launch_bounds__(256) void leconv_mfma(
    const short* __restrict__ Hb,
    const short* __restrict__ Wp1, const short* __restrict__ Wp2, const short* __restrict__ Wp3,
    const float* __restrict__ b1v, const float* __restrict__ b3v,
    float* __restrict__ D, short* __restrict__ Eb, short* __restrict__ Bb) {
    constexpr int K = K32 * 32;
    const int tid = threadIdx.x;
    const int wave = tid >> 6, lane = tid & 63;
    const int row_base = blockIdx.x * 64 + wave * 16;
    const int r15 = lane & 15, kg = lane >> 4;

    int arow = row_base + r15;
    if (arow >= N_NODES) arow = N_NODES - 1;
    const short* aptr = Hb + (size_t)arow * K + kg * 8;

    f32x4 acc1[8], acc2[8], acc3[8];
    #pragma unroll
    for (int t = 0; t < 8; t++) {
        acc1[t] = (f32x4)0.f; acc2[t] = (f32x4)0.f; acc3[t] = (f32x4)0.f;
    }

    #pragma unroll
    for (int kb = 0; kb < K32; kb++) {
        short8 a = *(const short8*)(aptr + kb * 32);
        #pragma unroll
        for (int t = 0; t < 8; t++) {
            const int widx = (kb * 8 + t) * 512 + lane * 8;
            short8 w1 = *(const short8*)(Wp1 + widx);
            short8 w2 = *(const short8*)(Wp2 + widx);
            short8 w3 = *(const short8*)(Wp3 + widx);
            acc1[t] = __builtin_amdgcn_mfma_f32_16x16x32_bf16(a, w1, acc1[t], 0, 0, 0);
            acc2[t] = __builtin_amdgcn_mfma_f32_16x16x32_bf16(a, w2, acc2[t], 0, 0, 0);
            acc3[t] = __builtin_amdgcn_mfma_f32_16x16x32_bf16(a, w3, acc3[t], 0, 0, 0);
        }
    }

    // C/D layout: col = lane&15 (within tile), row = (lane>>4)*4 + reg
    int grow[4];
    bool ok[4];
    #pragma unroll
    for (int i = 0; i < 4; i++) {
        grow[i] = row_base + kg * 4 + i;
        ok[i] = grow[i] < N_NODES;
    }
    #pragma unroll
    for (int t = 0; t < 8; t++) {
        const int c = t * 16 + r15;
        const float bb1 = b1v[c], bb3 = b3v[c];
        #pragma unroll
        for (int i = 0; i < 4; i++) {
            if (ok[i]) {
                size_t o = (size_t)grow[i] * HID + c;
                D[o] = acc1[t][i] + bb1;
                Eb[o] = bf16_bits(acc3[t][i] + bb3);
                Bb[o] = bf16_bits(acc2[t][i]);
            }
        }
    }
}

// ---------------- gather: Hb[i] = bf16(relu(cnt*D[i] - sum B[src] + E[i])) ----------------

__global__ __launch_bounds__(256) void gather_ll(const int* __restrict__ head,
                                                 const int2* __restrict__ edge_rec,
                                                 const short* __restrict__ Bb,
                                                 const float* __restrict__ D,
                                                 const short* __restrict__ Eb,
                                                 short* __restrict__ Hb) {
    const int wid = (blockIdx.x * 256 + threadIdx.x) >> 6;
    const int lane = threadIdx.x & 63;
    if (wid >= N_NODES) return;

    int e = head[wid];
    float ax = 0.f, ay = 0.f, cnt = 0.f;
    while (e >= 0) {
        const int2 rec = edge_rec[e];  // {src, next}
        const uint32_t u = *(const uint32_t*)(Bb + (size_t)rec.x * HID + lane * 2);
        ax += bf16_lo(u);
        ay += bf16_hi(u);
        cnt += 1.f;
        e = rec.y;
    }
    const float2 d2 = *(const float2*)(D + (size_t)wid * HID + lane * 2);
    const uint32_t ue = *(const uint32_t*)(Eb + (size_t)wid * HID + lane * 2);
    const float ox = fmaxf(fmaf(cnt, d2.x, bf16_lo(ue)) - ax, 0.f);
    const float oy = fmaxf(fmaf(cnt, d2.y, bf16_hi(ue)) - ay, 0.f);
    const uint32_t r = ((uint32_t)(uint16_t)bf16_bits(oy) << 16) | (uint16_t)bf16_bits(ox);
    *(uint32_t*)(Hb + (size_t)wid * HID + lane * 2) = r;
}

// ---------------- pool (mean of bf16 H) + FFN head ----------------

__global__ __launch_bounds__(128) void pool_ffn_kernel(const short* __restrict__ H,
                                                       const int* __restrict__ batch,
                                                       const float* __restrict__ Wf1,
                                                       const float* __restrict__ bf1,
                                                       const float* __restrict__ Wf2,
                                                       const float* __restrict__ bf2,
                                                       float* __restrict__ out) {
    const int g = blockIdx.x;
    const int t = threadIdx.x;  // 0..127

    int lo = 0, hi = N_NODES;
    while (lo < hi) { int mid = (lo + hi) >> 1; if (batch[mid] < g) lo = mid + 1; else hi = mid; }
    const int s = lo;
    hi = N_NODES;
    while (lo < hi) { int mid = (lo + hi) >> 1; if (batch[mid] < g + 1) lo = mid + 1; else hi = mid; }
    const int e = lo;

    float sum = 0.f;
    for (int n = s; n < e; n++) {
        short b = H[(size_t)n * HID + t];
        sum += __bfloat162float(*(__hip_bfloat16*)&b);
    }
    const float cntf = (float)(e - s);
    const float gx = sum / fmaxf(cntf, 1.f);

    __shared__ float lds[HID];
    lds[t] = gx;
    __syncthreads();

    float hsum = bf1[t];
    #pragma unroll 8
    for (int k = 0; k < HID; k++) hsum = fmaf(lds[k], Wf1[k * HID + t], hsum);
    const float hr = fmaxf(hsum, 0.f);

    float p0 = hr * Wf2[t * 2 + 0];
    float p1 = hr * Wf2[t * 2 + 1];
    #pragma unroll
    for (int off = 32; off > 0; off >>= 1) {
        p0 += __shfl_down(p0, off, 64);
        p1 += __shfl_down(p1, off, 64);
    }
    __shared__ float red[4];
    if ((t & 63) == 0) {
        red[(t >> 6) * 2 + 0] = p0;
        red[(t >> 6) * 2 + 1] = p1;
    }
    __syncthreads();
    if (t == 0) {
        out[g * 2 + 0] = red[0] + red[2] + bf2[0];
        out[g * 2 + 1] = red[1] + red[3] + bf2[1];
    }
}

// ---------------- launch ----------------

extern "C" void kernel_launch(void* const* d_in, const int* in_sizes, int n_in,
                              void* d_out, int out_size, void* d_ws, size_t ws_size,
                              hipStream_t stream) {
    (void)in_sizes; (void)n_in; (void)out_size; (void)ws_size;

    const float* x     = (const float*)d_in[0];
    const int*   ei    = (const int*)d_in[1];
    const int*   batch = (const int*)d_in[2];
    const float* W[9] = {
        (const float*)d_in[3],  (const float*)d_in[5],  (const float*)d_in[6],
        (const float*)d_in[8],  (const float*)d_in[10], (const float*)d_in[11],
        (const float*)d_in[13], (const float*)d_in[15], (const float*)d_in[16]};
    const float* b1_0 = (const float*)d_in[4];
    const float* b3_0 = (const float*)d_in[7];
    const float* b1_1 = (const float*)d_in[9];
    const float* b3_1 = (const float*)d_in[12];
    const float* b1_2 = (const float*)d_in[14];
    const float* b3_2 = (const float*)d_in[17];
    const float* Wf1  = (const float*)d_in[18];
    const float* bf1  = (const float*)d_in[19];
    const float* Wf2  = (const float*)d_in[20];
    const float* bf2  = (const float*)d_in[21];
    float* out = (float*)d_out;

    char* ws = (char*)d_ws;
    size_t off = 0;
    auto alloc = [&](size_t bytes) {
        void* p = ws + off;
        off += (bytes + 255) & ~(size_t)255;
        return p;
    };
    float* D       = (float*)alloc((size_t)N_NODES * HID * 4);
    short* Eb      = (short*)alloc((size_t)N_NODES * HID * 2);
    short* Bb      = (short*)alloc((size_t)N_NODES * HID * 2);
    short* Hb      = (short*)alloc((size_t)N_NODES * HID * 2);
    short* Xb      = (short*)alloc((size_t)N_NODES * 64 * 2);
    int2*  edge_rec= (int2*)alloc((size_t)N_EDGES * 8);
    int*   head    = (int*)alloc((size_t)N_NODES * 4);
    short* P[9];
    for (int m = 0; m < 9; m++) P[m] = (short*)alloc(16384 * 2);

    init_head<<<(N_NODES + 255) / 256, 256, 0, stream>>>(head);

    PackArgs pa;
    for (int m = 0; m < 9; m++) { pa.w[m] = W[m]; pa.o[m] = P[m]; }
    fused_prep<<<FILL_BLOCKS + CONV_BLOCKS + PACK_BLOCKS, 256, 0, stream>>>(
        ei, head, edge_rec, x, Xb, pa);

    const int gemm_grid = (N_NODES + 63) / 64;
    const int gather_grid = (N_NODES * 64 + 255) / 256;

    // layer 0
    leconv_mfma<2><<<gemm_grid, 256, 0, stream>>>(Xb, P[0], P[1], P[2], b1_0, b3_0, D, Eb, Bb);
    gather_ll<<<gather_grid, 256, 0, stream>>>(head, edge_rec, Bb, D, Eb, Hb);
    // layer 1
    leconv_mfma<4><<<gemm_grid, 256, 0, stream>>>(Hb, P[3], P[4], P[5], b1_1, b3_1, D, Eb, Bb);
    gather_ll<<<gather_grid, 256, 0, stream>>>(head, edge_rec, Bb, D, Eb, Hb);
    // layer 2
    leconv_mfma<4><<<gemm_grid, 256, 0, stream>>>(Hb, P[6], P[7], P[8], b1_2, b3_2, D, Eb, Bb);
    gather_ll<<<gather_grid, 256, 0, stream>>>(head, edge_rec, Bb, D, Eb, Hb);
    // pool + FFN
    pool_ffn_kernel<<<N_GRAPHS, 128, 0, stream>>>(Hb, batch, Wf1, bf1, Wf2, bf2, out);
}

// Round 5
// 518.352 us; speedup vs baseline: 1.5029x; 1.5029x over previous
//
#include <hip/hip_runtime.h>
#include <hip/hip_bf16.h>
#include <cstdint>

#define N_NODES 100000
#define N_EDGES 1600000
#define N_GRAPHS 2000
#define IN_DIM 37
#define HID 128

#define FILL_BLOCKS 6250   // 1.6M / 256
#define CONV_BLOCKS 6250   // 100k nodes * 16 quad-tasks / 256
#define PACK_BLOCKS 480    // (3*8192 + 6*16384) / 256
#define GEMM_GRID   1563   // (100000+63)/64

typedef __attribute__((ext_vector_type(8))) short short8;
typedef __attribute__((ext_vector_type(4))) float f32x4;

static __device__ __forceinline__ short bf16_bits(float f) {
    __hip_bfloat16 h = __float2bfloat16(f);
    return *reinterpret_cast<short*>(&h);
}
static __device__ __forceinline__ float bf16_lo(uint32_t u) {
    uint32_t v = u << 16;
    return *reinterpret_cast<float*>(&v);
}
static __device__ __forceinline__ float bf16_hi(uint32_t u) {
    uint32_t v = u & 0xffff0000u;
    return *reinterpret_cast<float*>(&v);
}

// ---------------- phase 1: hist(+rank) || x->bf16 convert || weight pack ----------------

struct PackArgs {
    const float* w[9];
    short* o[9];
};

__global__ __launch_bounds__(256) void fused_hist_conv_pack(const int* __restrict__ ei,
                                                            int* __restrict__ cnt,
                                                            int* __restrict__ rank,
                                                            const float* __restrict__ x,
                                                            short* __restrict__ Xb,
                                                            PackArgs pa) {
    const int b = blockIdx.x;
    const int tid = threadIdx.x;

    if (b < FILL_BLOCKS) {                       // hist + per-edge rank (ONLY atomic pass)
        const int e = b * 256 + tid;
        const int d = ei[N_EDGES + e];
        rank[e] = atomicAdd(&cnt[d], 1);
        return;
    }
    if (b < FILL_BLOCKS + CONV_BLOCKS) {         // x (fp32, 37) -> Xb (bf16, padded 64)
        const int idx = (b - FILL_BLOCKS) * 256 + tid;
        const int n = idx >> 4, j = idx & 15;
        const int k0 = j * 4;
        short4 o;
        o.x = (k0 + 0 < IN_DIM) ? bf16_bits(x[(size_t)n * IN_DIM + k0 + 0]) : (short)0;
        o.y = (k0 + 1 < IN_DIM) ? bf16_bits(x[(size_t)n * IN_DIM + k0 + 1]) : (short)0;
        o.z = (k0 + 2 < IN_DIM) ? bf16_bits(x[(size_t)n * IN_DIM + k0 + 2]) : (short)0;
        o.w = (k0 + 3 < IN_DIM) ? bf16_bits(x[(size_t)n * IN_DIM + k0 + 3]) : (short)0;
        *(short4*)(Xb + (size_t)n * 64 + k0) = o;
        return;
    }
    // pack: packed[kb*4096 + t*512 + lane*8 + i] = bf16(W[kb*32+(lane>>4)*8+i][t*16+(lane&15)])
    int idx = (b - FILL_BLOCKS - CONV_BLOCKS) * 256 + tid;
    int m, r, kin;
    if (idx < 24576) { m = idx >> 13; r = idx & 8191; kin = IN_DIM; }
    else { int q = idx - 24576; m = 3 + (q >> 14); r = q & 16383; kin = HID; }
    const int i = r & 7, lane = (r >> 3) & 63, t = (r >> 9) & 7, kb = r >> 12;
    const int k = kb * 32 + (lane >> 4) * 8 + i;
    const int c = t * 16 + (lane & 15);
    float v = (k < kin) ? pa.w[m][(size_t)k * HID + c] : 0.f;
    pa.o[m][r] = bf16_bits(v);
}

// ---------------- scan: cnt -> rowptr (+degf) ----------------

__global__ __launch_bounds__(1024) void scan_blocks(const int* __restrict__ cnt,
                                                    int* __restrict__ partial,
                                                    int* __restrict__ bsum) {
    __shared__ int ws[16];
    const int tid = threadIdx.x, lane = tid & 63, wv = tid >> 6;
    const int i = blockIdx.x * 1024 + tid;
    int v0 = (i < N_NODES) ? cnt[i] : 0;
    int v = v0;
    #pragma unroll
    for (int off = 1; off < 64; off <<= 1) {
        int n = __shfl_up(v, off, 64);
        if (lane >= off) v += n;
    }
    if (lane == 63) ws[wv] = v;
    __syncthreads();
    int woff = 0, tot = 0;
    #pragma unroll
    for (int w = 0; w < 16; w++) {
        int s = ws[w];
        if (w < wv) woff += s;
        tot += s;
    }
    if (i < N_NODES) partial[i] = woff + v - v0;
    if (tid == 0) bsum[blockIdx.x] = tot;
}

__global__ __launch_bounds__(1024) void scan_finalize(const int* __restrict__ partial,
                                                      const int* __restrict__ bsum,
                                                      const int* __restrict__ cnt,
                                                      int* __restrict__ rowptr,
                                                      float* __restrict__ degf) {
    __shared__ int off_s;
    const int tid = threadIdx.x, b = blockIdx.x;
    if (tid < 64) {
        int acc = 0;
        for (int j = tid; j < b; j += 64) acc += bsum[j];
        #pragma unroll
        for (int off = 32; off; off >>= 1) acc += __shfl_down(acc, off, 64);
        if (tid == 0) off_s = acc;
    }
    __syncthreads();
    const int i = b * 1024 + tid;
    if (i < N_NODES) {
        rowptr[i] = off_s + partial[i];
        degf[i] = (float)cnt[i];
    }
    if (b == 0 && tid == 0) rowptr[N_NODES] = N_EDGES;
}

// ---------------- LEConv GEMM body (MFMA bf16, fp32 accum) ----------------
// OUT = deg*(h@W1 + b1) + h@W3 + b3 (fp32), B = h@W2 (bf16)

template <int K32>
static __device__ __forceinline__ void leconv_body(
    int blk,
    const short* __restrict__ Hb,
    const short* __restrict__ Wp1, const short* __restrict__ Wp2, const short* __restrict__ Wp3,
    const float* __restrict__ b1v, const float* __restrict__ b3v,
    const float* __restrict__ deg,
    short* __restrict__ Bb, float* __restrict__ OUT) {
    constexpr int K = K32 * 32;
    const int tid = threadIdx.x;
    const int wave = tid >> 6, lane = tid & 63;
    const int row_base = blk * 64 + wave * 16;
    const int r15 = lane & 15, kg = lane >> 4;

    int arow = row_base + r15;
    if (arow >= N_NODES) arow = N_NODES - 1;
    const short* aptr = Hb + (size_t)arow * K + kg * 8;

    f32x4 acc1[8], acc2[8], acc3[8];
    #pragma unroll
    for (int t = 0; t < 8; t++) {
        acc1[t] = (f32x4)0.f; acc2[t] = (f32x4)0.f; acc3[t] = (f32x4)0.f;
    }

    #pragma unroll
    for (int kb = 0; kb < K32; kb++) {
        short8 a = *(const short8*)(aptr + kb * 32);
        #pragma unroll
        for (int t = 0; t < 8; t++) {
            const int widx = (kb * 8 + t) * 512 + lane * 8;
            short8 w1 = *(const short8*)(Wp1 + widx);
            short8 w2 = *(const short8*)(Wp2 + widx);
            short8 w3 = *(const short8*)(Wp3 + widx);
            acc1[t] = __builtin_amdgcn_mfma_f32_16x16x32_bf16(a, w1, acc1[t], 0, 0, 0);
            acc2[t] = __builtin_amdgcn_mfma_f32_16x16x32_bf16(a, w2, acc2[t], 0, 0, 0);
            acc3[t] = __builtin_amdgcn_mfma_f32_16x16x32_bf16(a, w3, acc3[t], 0, 0, 0);
        }
    }

    // C/D layout: col = lane&15, row = (lane>>4)*4 + reg
    int grow[4];
    bool ok[4];
    float dg[4];
    #pragma unroll
    for (int i = 0; i < 4; i++) {
        grow[i] = row_base + kg * 4 + i;
        ok[i] = grow[i] < N_NODES;
        dg[i] = ok[i] ? deg[grow[i]] : 0.f;
    }
    #pragma unroll
    for (int t = 0; t < 8; t++) {
        const int c = t * 16 + r15;
        const float bb1 = b1v[c], bb3 = b3v[c];
        #pragma unroll
        for (int i = 0; i < 4; i++) {
            if (ok[i]) {
                size_t o = (size_t)grow[i] * HID + c;
                OUT[o] = dg[i] * (acc1[t][i] + bb1) + acc3[t][i] + bb3;
                Bb[o] = bf16_bits(acc2[t][i]);
            }
        }
    }
}

template <int K32>
__global__ __launch_bounds__(256) void leconv_mfma(
    const short* __restrict__ Hb,
    const short* __restrict__ Wp1, const short* __restrict__ Wp2, const short* __restrict__ Wp3,
    const float* __restrict__ b1v, const float* __restrict__ b3v,
    const float* __restrict__ deg,
    short* __restrict__ Bb, float* __restrict__ OUT) {
    leconv_body<K32>(blockIdx.x, Hb, Wp1, Wp2, Wp3, b1v, b3v, deg, Bb, OUT);
}

// ---------------- phase 2: scatter col (no atomics) || layer-0 GEMM ----------------

__global__ __launch_bounds__(256) void fused_fill_gemm(
    const int* __restrict__ ei, const int* __restrict__ rank, const int* __restrict__ rowptr,
    int* __restrict__ col,
    const short* __restrict__ Xb,
    const short* __restrict__ Wp1, const short* __restrict__ Wp2, const short* __restrict__ Wp3,
    const float* __restrict__ b1v, const float* __restrict__ b3v,
    const float* __restrict__ deg,
    short* __restrict__ Bb, float* __restrict__ OUT) {
    const int b = blockIdx.x;
    if (b < FILL_BLOCKS) {
        const int e = b * 256 + threadIdx.x;
        const int s = ei[e];
        const int d = ei[N_EDGES + e];
        col[rowptr[d] + rank[e]] = s;
        return;
    }
    leconv_body<2>(b - FILL_BLOCKS, Xb, Wp1, Wp2, Wp3, b1v, b3v, deg, Bb, OUT);
}

// ---------------- gather: Hb[i] = bf16(relu(OUT[i] - sum_{e:dst=i} Bb[src(e)])) ----------------

__global__ __launch_bounds__(256) void gather_csr(const int* __restrict__ rowptr,
                                                  const int* __restrict__ col,
                                                  const short* __restrict__ Bb,
                                                  const float* __restrict__ OUT,
                                                  short* __restrict__ Hb) {
    const int wid = (blockIdx.x * 256 + threadIdx.x) >> 6;
    const int lane = threadIdx.x & 63;
    if (wid >= N_NODES) return;
    const int s = rowptr[wid], e = rowptr[wid + 1];
    float ax0 = 0.f, ay0 = 0.f, ax1 = 0.f, ay1 = 0.f;
    int t = s;
    for (; t + 4 <= e; t += 4) {
        const int c0 = col[t], c1 = col[t + 1], c2 = col[t + 2], c3 = col[t + 3];
        const uint32_t u0 = *(const uint32_t*)(Bb + (size_t)c0 * HID + lane * 2);
        const uint32_t u1 = *(const uint32_t*)(Bb + (size_t)c1 * HID + lane * 2);
        const uint32_t u2 = *(const uint32_t*)(Bb + (size_t)c2 * HID + lane * 2);
        const uint32_t u3 = *(const uint32_t*)(Bb + (size_t)c3 * HID + lane * 2);
        ax0 += bf16_lo(u0) + bf16_lo(u2);
        ay0 += bf16_hi(u0) + bf16_hi(u2);
        ax1 += bf16_lo(u1) + bf16_lo(u3);
        ay1 += bf16_hi(u1) + bf16_hi(u3);
    }
    for (; t < e; t++) {
        const int c0 = col[t];
        const uint32_t u0 = *(const uint32_t*)(Bb + (size_t)c0 * HID + lane * 2);
        ax0 += bf16_lo(u0);
        ay0 += bf16_hi(u0);
    }
    const float ax = ax0 + ax1, ay = ay0 + ay1;
    const float2 o = *(const float2*)(OUT + (size_t)wid * HID + lane * 2);
    const float ox = fmaxf(o.x - ax, 0.f);
    const float oy = fmaxf(o.y - ay, 0.f);
    const uint32_t r = ((uint32_t)(uint16_t)bf16_bits(oy) << 16) | (uint16_t)bf16_bits(ox);
    *(uint32_t*)(Hb + (size_t)wid * HID + lane * 2) = r;
}

// ---------------- pool (mean of bf16 H) + FFN head ----------------

__global__ __launch_bounds__(128) void pool_ffn_kernel(const short* __restrict__ H,
                                                       const int* __restrict__ batch,
                                                       const float* __restrict__ Wf1,
                                                       const float* __restrict__ bf1,
                                                       const float* __restrict__ Wf2,
                                                       const float* __restrict__ bf2,
                                                       float* __restrict__ out) {
    const int g = blockIdx.x;
    const int t = threadIdx.x;  // 0..127

    int lo = 0, hi = N_NODES;
    while (lo < hi) { int mid = (lo + hi) >> 1; if (batch[mid] < g) lo = mid + 1; else hi = mid; }
    const int s = lo;
    hi = N_NODES;
    while (lo < hi) { int mid = (lo + hi) >> 1; if (batch[mid] < g + 1) lo = mid + 1; else hi = mid; }
    const int e = lo;

    float sum = 0.f;
    for (int n = s; n < e; n++) {
        short b = H[(size_t)n * HID + t];
        sum += __bfloat162float(*(__hip_bfloat16*)&b);
    }
    const float cntf = (float)(e - s);
    const float gx = sum / fmaxf(cntf, 1.f);

    __shared__ float lds[HID];
    lds[t] = gx;
    __syncthreads();

    float hsum = bf1[t];
    #pragma unroll 8
    for (int k = 0; k < HID; k++) hsum = fmaf(lds[k], Wf1[k * HID + t], hsum);
    const float hr = fmaxf(hsum, 0.f);

    float p0 = hr * Wf2[t * 2 + 0];
    float p1 = hr * Wf2[t * 2 + 1];
    #pragma unroll
    for (int off = 32; off > 0; off >>= 1) {
        p0 += __shfl_down(p0, off, 64);
        p1 += __shfl_down(p1, off, 64);
    }
    __shared__ float red[4];
    if ((t & 63) == 0) {
        red[(t >> 6) * 2 + 0] = p0;
        red[(t >> 6) * 2 + 1] = p1;
    }
    __syncthreads();
    if (t == 0) {
        out[g * 2 + 0] = red[0] + red[2] + bf2[0];
        out[g * 2 + 1] = red[1] + red[3] + bf2[1];
    }
}

// ---------------- launch ----------------

extern "C" void kernel_launch(void* const* d_in, const int* in_sizes, int n_in,
                              void* d_out, int out_size, void* d_ws, size_t ws_size,
                              hipStream_t stream) {
    (void)in_sizes; (void)n_in; (void)out_size; (void)ws_size;

    const float* x     = (const float*)d_in[0];
    const int*   ei    = (const int*)d_in[1];
    const int*   batch = (const int*)d_in[2];
    const float* W[9] = {
        (const float*)d_in[3],  (const float*)d_in[5],  (const float*)d_in[6],
        (const float*)d_in[8],  (const float*)d_in[10], (const float*)d_in[11],
        (const float*)d_in[13], (const float*)d_in[15], (const float*)d_in[16]};
    const float* b1_0 = (const float*)d_in[4];
    const float* b3_0 = (const float*)d_in[7];
    const float* b1_1 = (const float*)d_in[9];
    const float* b3_1 = (const float*)d_in[12];
    const float* b1_2 = (const float*)d_in[14];
    const float* b3_2 = (const float*)d_in[17];
    const float* Wf1  = (const float*)d_in[18];
    const float* bf1  = (const float*)d_in[19];
    const float* Wf2  = (const float*)d_in[20];
    const float* bf2  = (const float*)d_in[21];
    float* out = (float*)d_out;

    char* ws = (char*)d_ws;
    size_t off = 0;
    auto alloc = [&](size_t bytes) {
        void* p = ws + off;
        off += (bytes + 255) & ~(size_t)255;
        return p;
    };
    float* OUT    = (float*)alloc((size_t)N_NODES * HID * 4);
    short* Bb     = (short*)alloc((size_t)N_NODES * HID * 2);
    short* Hb     = (short*)alloc((size_t)N_NODES * HID * 2);
    short* Xb     = (short*)alloc((size_t)N_NODES * 64 * 2);
    float* degf   = (float*)alloc((size_t)N_NODES * 4);
    int*   rowptr = (int*)alloc((size_t)(N_NODES + 1) * 4);
    int*   cnt    = (int*)alloc((size_t)N_NODES * 4);
    int*   col    = (int*)alloc((size_t)N_EDGES * 4);
    int*   rank   = (int*)alloc((size_t)N_EDGES * 4);
    int*   partial= (int*)alloc((size_t)N_NODES * 4);
    int*   bsum   = (int*)alloc(1024);
    short* P[9];
    for (int m = 0; m < 9; m++) P[m] = (short*)alloc(16384 * 2);

    hipMemsetAsync(cnt, 0, (size_t)N_NODES * 4, stream);

    PackArgs pa;
    for (int m = 0; m < 9; m++) { pa.w[m] = W[m]; pa.o[m] = P[m]; }

    // phase 1: hist(+rank) || x convert || weight pack
    fused_hist_conv_pack<<<FILL_BLOCKS + CONV_BLOCKS + PACK_BLOCKS, 256, 0, stream>>>(
        ei, cnt, rank, x, Xb, pa);

    // scan
    const int NSB = (N_NODES + 1023) / 1024;  // 98
    scan_blocks<<<NSB, 1024, 0, stream>>>(cnt, partial, bsum);
    scan_finalize<<<NSB, 1024, 0, stream>>>(partial, bsum, cnt, rowptr, degf);

    // phase 2: scatter col (no atomics) || layer-0 GEMM
    fused_fill_gemm<<<FILL_BLOCKS + GEMM_GRID, 256, 0, stream>>>(
        ei, rank, rowptr, col, Xb, P[0], P[1], P[2], b1_0, b3_0, degf, Bb, OUT);

    const int gather_grid = (N_NODES * 64 + 255) / 256;  // 25000

    gather_csr<<<gather_grid, 256, 0, stream>>>(rowptr, col, Bb, OUT, Hb);
    // layer 1
    leconv_mfma<4><<<GEMM_GRID, 256, 0, stream>>>(Hb, P[3], P[4], P[5], b1_1, b3_1, degf, Bb, OUT);
    gather_csr<<<gather_grid, 256, 0, stream>>>(rowptr, col, Bb, OUT, Hb);
    // layer 2
    leconv_mfma<4><<<GEMM_GRID, 256, 0, stream>>>(Hb, P[6], P[7], P[8], b1_2, b3_2, degf, Bb, OUT);
    gather_csr<<<gather_grid, 256, 0, stream>>>(rowptr, col, Bb, OUT, Hb);
    // pool + FFN
    pool_ffn_kernel<<<N_GRAPHS, 128, 0, stream>>>(Hb, batch, Wf1, bf1, Wf2, bf2, out);
}